// Round 1
// baseline (376.786 us; speedup 1.0000x reference)
//
#include <hip/hip_runtime.h>
#include <hip/hip_bf16.h>

#define BB 2
#define SS 2048
#define HH 2048
#define NHH 16
#define HDD 128

using f32x4  = __attribute__((ext_vector_type(4))) float;
using bf16x8 = __attribute__((ext_vector_type(8))) short;

__device__ __forceinline__ unsigned short f2bf(float x) {
  unsigned int u = __float_as_uint(x);
  unsigned int r = (u + 0x7FFFu + ((u >> 16) & 1u)) >> 16;
  return (unsigned short)r;
}
__device__ __forceinline__ float bf2f(unsigned short u) {
  return __uint_as_float(((unsigned int)u) << 16);
}

__device__ __forceinline__ void gll16(const void* g, void* l) {
  __builtin_amdgcn_global_load_lds(
      (__attribute__((address_space(1))) void*)(g),
      (__attribute__((address_space(3))) void*)(l), 16, 0, 0);
}

// ---------------- converts + rope table ----------------

__global__ void convert_bf16(const float* __restrict__ in, unsigned short* __restrict__ out, int n4) {
  int i = blockIdx.x * blockDim.x + threadIdx.x;
  if (i >= n4) return;
  float4 v = reinterpret_cast<const float4*>(in)[i];
  ushort4 o;
  o.x = f2bf(v.x); o.y = f2bf(v.y); o.z = f2bf(v.z); o.w = f2bf(v.w);
  reinterpret_cast<ushort4*>(out)[i] = o;
}

__global__ void build_tab(float* __restrict__ tab) { // [S][64][2] = cos,sin
  int i = blockIdx.x * blockDim.x + threadIdx.x;
  if (i >= SS * 64) return;
  int s = i >> 6, j = i & 63;
  float invf = expf(-logf(10000.f) * ((float)j / 64.f));
  float a = (float)s * invf;
  tab[i * 2]     = cosf(a);
  tab[i * 2 + 1] = sinf(a);
}

// ---------------- 256x256 deep-pipelined bt-GEMM (ring-4 LDS, counted vmcnt) ----
// C[M,N] = A[M,K] * W[N,K]^T. 512 threads = 8 waves (2M x 4N), wave tile 128x64.
// BK=32. LDS ring of 4 K-tiles; tile t+3 staged while computing tile t.
// Steady state: 12 global_load_lds outstanding per thread; s_waitcnt vmcnt(8)
// retires exactly tile t's 4 loads. Never vmcnt(0) in main loop.

template<int MODE>
__global__ __launch_bounds__(512, 2)
void gemm256(const unsigned short* __restrict__ A,
             const unsigned short* __restrict__ Bw,
             const float* __restrict__ bias,
             float* __restrict__ outF,
             unsigned short* __restrict__ outQ,
             unsigned short* __restrict__ outK,
             unsigned short* __restrict__ outV,
             int Kdim) {
  __shared__ unsigned short lA[4][256 * 32];   // 64 KB
  __shared__ unsigned short lB[4][256 * 32];   // 64 KB
  const int tid = threadIdx.x;
  const int tn = blockIdx.x, tm = blockIdx.y;
  const int wid = tid >> 6, lane = tid & 63;
  const int wm = wid >> 2, wn = wid & 3;       // 2 x 4 wave grid
  const int lr = lane & 15, lg = lane >> 4;

  const unsigned short* Ab = A + (size_t)tm * 256 * Kdim;
  const unsigned short* Bb = Bw + (size_t)tn * 256 * Kdim;

  f32x4 acc[8][4] = {};

  // Stage K-tile t into ring slot t&3. 4 gll16/thread (2 for A, 2 for B).
  // LDS dest linear (wave-uniform base + lane*16); global src pre-swizzled:
  // chunk_global = chunk_lds ^ ((row>>1)&3)  (involution, matched on read).
  auto STAGE = [&](int t) {
    const int k0 = t * 32;
    unsigned short* da = lA[t & 3];
    unsigned short* db = lB[t & 3];
#pragma unroll
    for (int p = 0; p < 2; ++p) {
      int cl = p * 512 + tid;              // 0..1023 chunk index (16B chunks)
      int row = cl >> 2, cc = cl & 3;
      int cg = cc ^ ((row >> 1) & 3);
      gll16(Ab + (size_t)row * Kdim + k0 + cg * 8, da + cl * 8);
      gll16(Bb + (size_t)row * Kdim + k0 + cg * 8, db + cl * 8);
    }
  };

  const int nt = Kdim >> 5;
  STAGE(0); STAGE(1); STAGE(2);            // 12 loads in flight

  for (int t = 0; t < nt; ++t) {
    // retire tile t's staging (wave-local), then sync all waves
    if (t < nt - 2)       asm volatile("s_waitcnt vmcnt(8)" ::: "memory");
    else if (t == nt - 2) asm volatile("s_waitcnt vmcnt(4)" ::: "memory");
    else                  asm volatile("s_waitcnt vmcnt(0)" ::: "memory");
    __builtin_amdgcn_s_barrier();
    __builtin_amdgcn_sched_barrier(0);

    if (t + 3 < nt) STAGE(t + 3);          // overwrites slot last read at t-1

    const unsigned short* la = lA[t & 3];
    const unsigned short* lb = lB[t & 3];
    bf16x8 af[8], bfr[4];
#pragma unroll
    for (int mi = 0; mi < 8; ++mi) {
      int ra = wm * 128 + mi * 16 + lr;
      af[mi] = *reinterpret_cast<const bf16x8*>(la + ra * 32 + ((lg ^ ((ra >> 1) & 3)) << 3));
    }
#pragma unroll
    for (int ni = 0; ni < 4; ++ni) {
      int rb = wn * 64 + ni * 16 + lr;
      bfr[ni] = *reinterpret_cast<const bf16x8*>(lb + rb * 32 + ((lg ^ ((rb >> 1) & 3)) << 3));
    }
    __builtin_amdgcn_s_setprio(1);
#pragma unroll
    for (int mi = 0; mi < 8; ++mi)
#pragma unroll
      for (int ni = 0; ni < 4; ++ni)
        acc[mi][ni] = __builtin_amdgcn_mfma_f32_16x16x32_bf16(af[mi], bfr[ni], acc[mi][ni], 0, 0, 0);
    __builtin_amdgcn_s_setprio(0);
  }

#pragma unroll
  for (int mi = 0; mi < 8; ++mi) {
#pragma unroll
    for (int ni = 0; ni < 4; ++ni) {
      int n = tn * 256 + wn * 64 + ni * 16 + lr;
#pragma unroll
      for (int r = 0; r < 4; ++r) {
        int m = tm * 256 + wm * 128 + mi * 16 + lg * 4 + r;
        float v = acc[mi][ni][r];
        if (MODE == 1) {
          v += bias[n];
          int sel = n >> 11;
          int h = (n >> 7) & 15;
          int d = n & 127;
          int b = m >> 11;
          int s = m & 2047;
          if (sel == 0)
            outQ[(((size_t)(b * 16 + h)) * 2048 + s) * 128 + d] = f2bf(v);
          else if (sel == 1)
            outK[(((size_t)(b * 16 + h)) * 2048 + s) * 128 + d] = f2bf(v);
          else
            outV[(((size_t)(b * 16 + h)) * 128 + d) * 2048 + s] = f2bf(v);
        } else {
          outF[(size_t)m * 2048 + n] = v;
        }
      }
    }
  }
}

// ---------------- legacy 128x128 bt-GEMM (kept for the output projection) ----

template<int MODE>
__global__ __launch_bounds__(256)
void gemm_bt(const unsigned short* __restrict__ A,
             const unsigned short* __restrict__ Bw,
             const float* __restrict__ bias,
             float* __restrict__ outF,
             unsigned short* __restrict__ outQ,
             unsigned short* __restrict__ outK,
             unsigned short* __restrict__ outV,
             int Kdim) {
  __shared__ unsigned short lA[128 * 32];
  __shared__ unsigned short lB[128 * 32];
  const int tid = threadIdx.x;
  const int tn = blockIdx.x, tm = blockIdx.y;
  const int wid = tid >> 6, lane = tid & 63;
  const int wm = wid >> 1, wn = wid & 1;
  const int lr = lane & 15, lg = lane >> 4;

  f32x4 acc[4][4] = {};

  const unsigned short* Abase = A + (size_t)tm * 128 * Kdim;
  const unsigned short* Bbase = Bw + (size_t)tn * 128 * Kdim;

  for (int k0 = 0; k0 < Kdim; k0 += 32) {
#pragma unroll
    for (int ch = 0; ch < 2; ++ch) {
      int c = tid + ch * 256;
      int row = c >> 2;
      int cb = c & 3;
      gll16(Abase + (size_t)row * Kdim + k0 + ((cb ^ (row & 3)) << 3), lA + c * 8);
      gll16(Bbase + (size_t)row * Kdim + k0 + ((cb ^ (row & 3)) << 3), lB + c * 8);
    }
    __syncthreads();
    bf16x8 af[4], bfr[4];
#pragma unroll
    for (int t = 0; t < 4; ++t) {
      int ra = wm * 64 + t * 16 + lr;
      int rb = wn * 64 + t * 16 + lr;
      af[t]  = *reinterpret_cast<const bf16x8*>(lA + ra * 32 + ((lg ^ (ra & 3)) << 3));
      bfr[t] = *reinterpret_cast<const bf16x8*>(lB + rb * 32 + ((lg ^ (rb & 3)) << 3));
    }
#pragma unroll
    for (int i = 0; i < 4; ++i)
#pragma unroll
      for (int j = 0; j < 4; ++j)
        acc[i][j] = __builtin_amdgcn_mfma_f32_16x16x32_bf16(af[i], bfr[j], acc[i][j], 0, 0, 0);
    __syncthreads();
  }

#pragma unroll
  for (int i = 0; i < 4; ++i) {
#pragma unroll
    for (int j = 0; j < 4; ++j) {
      int n = tn * 128 + wn * 64 + j * 16 + lr;
#pragma unroll
      for (int r = 0; r < 4; ++r) {
        int m = tm * 128 + wm * 64 + i * 16 + lg * 4 + r;
        float v = acc[i][j][r];
        if (MODE == 1) {
          v += bias[n];
          int sel = n >> 11;
          int h = (n >> 7) & 15;
          int d = n & 127;
          int b = m >> 11;
          int s = m & 2047;
          if (sel == 0)
            outQ[(((size_t)(b * 16 + h)) * 2048 + s) * 128 + d] = f2bf(v);
          else if (sel == 1)
            outK[(((size_t)(b * 16 + h)) * 2048 + s) * 128 + d] = f2bf(v);
          else
            outV[(((size_t)(b * 16 + h)) * 128 + d) * 2048 + s] = f2bf(v);
        } else {
          outF[(size_t)m * 2048 + n] = v;
        }
      }
    }
  }
}

// ---------------- in-place RoPE on Q,K ----------------

__global__ void rope_inplace(unsigned short* __restrict__ Qr, unsigned short* __restrict__ Kr,
                             const int* __restrict__ pos, const float* __restrict__ tab) {
  int i = blockIdx.x * blockDim.x + threadIdx.x; // 2^20 threads
  if (i >= (1 << 20)) return;
  int jb = i & 7;
  int s  = (i >> 3) & 2047;
  int bh = (i >> 14) & 31;
  int a  = i >> 19;
  unsigned short* base = (a ? Kr : Qr) + (((size_t)bh * 2048 + s) * 128);
  int b = bh >> 4;
  int p = pos[b * 2048 + s];
  bf16x8 x1 = *reinterpret_cast<bf16x8*>(base + jb * 8);
  bf16x8 x2 = *reinterpret_cast<bf16x8*>(base + 64 + jb * 8);
  bf16x8 y1, y2;
#pragma unroll
  for (int t = 0; t < 8; ++t) {
    int j = jb * 8 + t;
    float c  = tab[((size_t)p * 64 + j) * 2];
    float sn = tab[((size_t)p * 64 + j) * 2 + 1];
    float a1 = bf2f((unsigned short)x1[t]);
    float a2 = bf2f((unsigned short)x2[t]);
    y1[t] = (short)f2bf(a1 * c - a2 * sn);
    y2[t] = (short)f2bf(a2 * c + a1 * sn);
  }
  *reinterpret_cast<bf16x8*>(base + jb * 8) = y1;
  *reinterpret_cast<bf16x8*>(base + 64 + jb * 8) = y2;
}

// ---------------- flash attention (causal, work-balanced) ----------------
// Block bx handles q-tiles {31-bx, bx}: every block does exactly 33 K-iters.

__global__ __launch_bounds__(256)
void attn_fwd(const unsigned short* __restrict__ Qr,
              const unsigned short* __restrict__ Kr,
              const unsigned short* __restrict__ Vt,
              unsigned short* __restrict__ attnb) {
  __shared__ unsigned short Ks[64 * 128];
  __shared__ unsigned short Vs[128 * 64];
  __shared__ unsigned short Ps[64 * 64];
  const int bx = blockIdx.x, bh = blockIdx.y;
  const int tid = threadIdx.x;
  const int wid = tid >> 6, lane = tid & 63;
  const int lr = lane & 15, lg = lane >> 4;
  const unsigned short* Qb = Qr + (size_t)bh * SS * HDD;
  const unsigned short* Kb = Kr + (size_t)bh * SS * HDD;
  const unsigned short* Vb = Vt + (size_t)bh * HDD * SS;
  const int b = bh >> 4, h = bh & 15;

#pragma unroll 1
  for (int qi = 0; qi < 2; ++qi) {
    const int qt = qi ? bx : (31 - bx);

    bf16x8 qf[4];
#pragma unroll
    for (int kk = 0; kk < 4; ++kk)
      qf[kk] = *reinterpret_cast<const bf16x8*>(
          Qb + ((size_t)(qt * 64 + wid * 16 + lr)) * 128 + kk * 32 + lg * 8);

    f32x4 oacc[8] = {};
    float mrow[4], lsum[4];
#pragma unroll
    for (int r = 0; r < 4; ++r) { mrow[r] = -1e30f; lsum[r] = 0.f; }

    for (int kt = 0; kt <= qt; ++kt) {
#pragma unroll
      for (int ch = 0; ch < 4; ++ch) {
        int c = tid + ch * 256;
        {
          int row = c >> 4, cb = c & 15;
          gll16(Kb + ((size_t)(kt * 64 + row)) * 128 + ((cb ^ (row & 7)) << 3), Ks + c * 8);
        }
        {
          int row = c >> 3, cb = c & 7;
          gll16(Vb + (size_t)row * SS + kt * 64 + ((cb ^ (row & 7)) << 3), Vs + c * 8);
        }
      }
      __syncthreads();

      float sv[4][4];
#pragma unroll
      for (int nt = 0; nt < 4; ++nt) {
        f32x4 sa = {};
#pragma unroll
        for (int kk = 0; kk < 4; ++kk) {
          int row = nt * 16 + lr;
          bf16x8 kf = *reinterpret_cast<const bf16x8*>(
              Ks + row * 128 + (((kk * 4 + lg) ^ (row & 7)) << 3));
          sa = __builtin_amdgcn_mfma_f32_16x16x32_bf16(qf[kk], kf, sa, 0, 0, 0);
        }
#pragma unroll
        for (int r = 0; r < 4; ++r) {
          float s = sa[r] * 0.088388347648318447f; // 1/sqrt(128)
          if (kt == qt && (nt * 16 + lr) > (wid * 16 + lg * 4 + r)) s -= 1e9f;
          sv[nt][r] = s;
        }
      }

      float tmax[4];
#pragma unroll
      for (int r = 0; r < 4; ++r)
        tmax[r] = fmaxf(fmaxf(sv[0][r], sv[1][r]), fmaxf(sv[2][r], sv[3][r]));
#pragma unroll
      for (int r = 0; r < 4; ++r) {
        tmax[r] = fmaxf(tmax[r], __shfl_xor(tmax[r], 1));
        tmax[r] = fmaxf(tmax[r], __shfl_xor(tmax[r], 2));
        tmax[r] = fmaxf(tmax[r], __shfl_xor(tmax[r], 4));
        tmax[r] = fmaxf(tmax[r], __shfl_xor(tmax[r], 8));
      }
      float fr[4], tsum[4];
#pragma unroll
      for (int r = 0; r < 4; ++r) {
        float mn = fmaxf(mrow[r], tmax[r]);
        fr[r] = __expf(mrow[r] - mn);
        mrow[r] = mn;
        tsum[r] = 0.f;
      }
#pragma unroll
      for (int nt = 0; nt < 4; ++nt) {
        int colc = nt * 2 + (lr >> 3);
#pragma unroll
        for (int r = 0; r < 4; ++r) {
          float p = __expf(sv[nt][r] - mrow[r]);
          tsum[r] += p;
          int row = wid * 16 + lg * 4 + r;
          Ps[row * 64 + ((colc ^ (row & 7)) << 3) + (lr & 7)] = f2bf(p);
        }
      }
#pragma unroll
      for (int r = 0; r < 4; ++r) {
        tsum[r] += __shfl_xor(tsum[r], 1);
        tsum[r] += __shfl_xor(tsum[r], 2);
        tsum[r] += __shfl_xor(tsum[r], 4);
        tsum[r] += __shfl_xor(tsum[r], 8);
        lsum[r] = lsum[r] * fr[r] + tsum[r];
      }
#pragma unroll
      for (int ct = 0; ct < 8; ++ct)
#pragma unroll
        for (int r = 0; r < 4; ++r)
          oacc[ct][r] *= fr[r];

      bf16x8 pf[2];
#pragma unroll
      for (int ks = 0; ks < 2; ++ks) {
        int row = wid * 16 + lr;
        pf[ks] = *reinterpret_cast<const bf16x8*>(
            Ps + row * 64 + (((ks * 4 + lg) ^ (row & 7)) << 3));
      }
#pragma unroll
      for (int ct = 0; ct < 8; ++ct) {
#pragma unroll
        for (int ks = 0; ks < 2; ++ks) {
          int row = ct * 16 + lr;
          bf16x8 vf = *reinterpret_cast<const bf16x8*>(
              Vs + row * 64 + (((ks * 4 + lg) ^ (row & 7)) << 3));
          oacc[ct] = __builtin_amdgcn_mfma_f32_16x16x32_bf16(pf[ks], vf, oacc[ct], 0, 0, 0);
        }
      }
      __syncthreads();
    }

#pragma unroll
    for (int r = 0; r < 4; ++r) {
      float rl = 1.f / lsum[r];
      int qg = qt * 64 + wid * 16 + lg * 4 + r;
#pragma unroll
      for (int ct = 0; ct < 8; ++ct) {
        int d = ct * 16 + lr;
        attnb[((size_t)b * SS + qg) * HH + h * 128 + d] = f2bf(oacc[ct][r] * rl);
      }
    }
  }
}

// ---------------- launch ----------------

extern "C" void kernel_launch(void* const* d_in, const int* in_sizes, int n_in,
                              void* d_out, int out_size, void* d_ws, size_t ws_size,
                              hipStream_t stream) {
  const float* hs     = (const float*)d_in[0];
  const int*   pos    = (const int*)d_in[1];
  const float* qkv_w  = (const float*)d_in[3];
  const float* qkv_b  = (const float*)d_in[4];
  const float* o_w    = (const float*)d_in[5];
  float* out = (float*)d_out;
  char* ws = (char*)d_ws;

  unsigned short* hsb   = (unsigned short*)(ws);                  // 16 MB
  unsigned short* wqkvb = (unsigned short*)(ws + 16777216);       // 24 MB
  unsigned short* owb   = (unsigned short*)(ws + 41943040);       // 8 MB
  unsigned short* Qr    = (unsigned short*)(ws + 50331648);       // 16 MB
  unsigned short* Kr    = (unsigned short*)(ws + 67108864);       // 16 MB
  unsigned short* Vt    = (unsigned short*)(ws + 83886080);       // 16 MB
  unsigned short* attnb = (unsigned short*)(ws + 100663296);      // 16 MB
  float*          tab   = (float*)(ws + 117440512);               // 1 MB

  convert_bf16<<<2097152 / 256, 256, 0, stream>>>(hs, hsb, 2097152);
  convert_bf16<<<3145728 / 256, 256, 0, stream>>>(qkv_w, wqkvb, 3145728);
  convert_bf16<<<1048576 / 256, 256, 0, stream>>>(o_w, owb, 1048576);
  build_tab<<<512, 256, 0, stream>>>(tab);

  gemm256<1><<<dim3(24, 16), 512, 0, stream>>>(hsb, wqkvb, qkv_b, nullptr, Qr, Kr, Vt, 2048);
  rope_inplace<<<4096, 256, 0, stream>>>(Qr, Kr, pos, tab);
  attn_fwd<<<dim3(16, 32), 256, 0, stream>>>(Qr, Kr, Vt, attnb);
  gemm_bt<0><<<dim3(16, 32), 256, 0, stream>>>(attnb, owb, nullptr, out, nullptr, nullptr, nullptr, 2048);
}

// Round 2
// 339.599 us; speedup vs baseline: 1.1095x; 1.1095x over previous
//
#include <hip/hip_runtime.h>
#include <hip/hip_bf16.h>

#define BB 2
#define SS 2048
#define HH 2048
#define NHH 16
#define HDD 128

using f32x4  = __attribute__((ext_vector_type(4))) float;
using bf16x8 = __attribute__((ext_vector_type(8))) short;

__device__ __forceinline__ unsigned short f2bf(float x) {
  unsigned int u = __float_as_uint(x);
  unsigned int r = (u + 0x7FFFu + ((u >> 16) & 1u)) >> 16;
  return (unsigned short)r;
}
__device__ __forceinline__ float bf2f(unsigned short u) {
  return __uint_as_float(((unsigned int)u) << 16);
}

__device__ __forceinline__ void gll16(const void* g, void* l) {
  __builtin_amdgcn_global_load_lds(
      (__attribute__((address_space(1))) void*)(g),
      (__attribute__((address_space(3))) void*)(l), 16, 0, 0);
}

#define MFMA16(a, b, c) __builtin_amdgcn_mfma_f32_16x16x32_bf16(a, b, c, 0, 0, 0)

// ---------------- converts + rope table ----------------

__global__ void convert_bf16(const float* __restrict__ in, unsigned short* __restrict__ out, int n4) {
  int i = blockIdx.x * blockDim.x + threadIdx.x;
  if (i >= n4) return;
  float4 v = reinterpret_cast<const float4*>(in)[i];
  ushort4 o;
  o.x = f2bf(v.x); o.y = f2bf(v.y); o.z = f2bf(v.z); o.w = f2bf(v.w);
  reinterpret_cast<ushort4*>(out)[i] = o;
}

__global__ void build_tab(float* __restrict__ tab) { // [S][64][2] = cos,sin
  int i = blockIdx.x * blockDim.x + threadIdx.x;
  if (i >= SS * 64) return;
  int s = i >> 6, j = i & 63;
  float invf = expf(-logf(10000.f) * ((float)j / 64.f));
  float a = (float)s * invf;
  tab[i * 2]     = cosf(a);
  tab[i * 2 + 1] = sinf(a);
}

// ---------------- 256x256 8-phase bt-GEMM (T2+T3+T4+T5, m201 structure) --------
// C[M,N] = A[M,K] * W[N,K]^T. 512 threads = 8 waves (2M x 4N), wave tile 128x64.
// BK=64, 2-slot LDS double buffer (128 KB). 4 phases per K-tile, each phase:
//   {ds_read frag subtile ; stage 1 half-tile ; barrier ; lgkmcnt(0) ; 16 MFMA ; barrier}
// vmcnt(6) only at phase 4 (retires exactly tile g+1's 4 halves; 3 halves stay
// in flight across barriers). Stage halves = per-phase consumption row-sets:
//   A-half h: rows r+(r&64)+h*64  (phase1 reads h=0, phase2 h=1)
//   B-half h: rows ((r>>5)<<6)+(r&31)+h*32 (phase1 reads h=0, phase3 h=1)
// Swizzle: 16B chunk c stored at c^(row&7) (pre-swizzled global src, matched on
// ds_read) -> 2-way residual conflict only (free).

template<int MODE>
__global__ __launch_bounds__(512, 1)
void gemm8p(const unsigned short* __restrict__ A,
            const unsigned short* __restrict__ Bw,
            const float* __restrict__ bias,
            float* __restrict__ outF,
            unsigned short* __restrict__ outQ,
            unsigned short* __restrict__ outK,
            unsigned short* __restrict__ outV,
            int Kdim) {
  __shared__ unsigned short lA[2][256 * 64];   // 64 KB
  __shared__ unsigned short lB[2][256 * 64];   // 64 KB
  const int tid = threadIdx.x;
  const int tn = blockIdx.x, tm = blockIdx.y;
  const int wid = tid >> 6, lane = tid & 63;
  const int wm = wid >> 2, wn = wid & 3;       // 2 x 4 wave grid
  const int lr = lane & 15, lg = lane >> 4;

  const unsigned short* Ab = A + (size_t)tm * 256 * Kdim;
  const unsigned short* Bb = Bw + (size_t)tn * 256 * Kdim;

  f32x4 acc[8][4] = {};
  bf16x8 af[8][2], bfr[4][2];

  const int nt = Kdim >> 6;

  auto stageA = [&](int t, int h) {
    unsigned short* L = lA[t & 1];
    const int k0 = t << 6;
#pragma unroll
    for (int p = 0; p < 2; ++p) {
      int cl = p * 512 + tid;
      int r = cl >> 3, c = cl & 7;
      int row = r + (r & 64) + (h << 6);
      int cg = c ^ (row & 7);
      gll16(Ab + (size_t)row * Kdim + k0 + (cg << 3), L + row * 64 + (c << 3));
    }
  };
  auto stageB = [&](int t, int h) {
    unsigned short* L = lB[t & 1];
    const int k0 = t << 6;
#pragma unroll
    for (int p = 0; p < 2; ++p) {
      int cl = p * 512 + tid;
      int r = cl >> 3, c = cl & 7;
      int row = ((r >> 5) << 6) + (r & 31) + (h << 5);
      int cg = c ^ (row & 7);
      gll16(Bb + (size_t)row * Kdim + k0 + (cg << 3), L + row * 64 + (c << 3));
    }
  };
  auto rdA = [&](const unsigned short* la, int mi, int ks) -> bf16x8 {
    int ra = wm * 128 + mi * 16 + lr;
    return *reinterpret_cast<const bf16x8*>(la + ra * 64 + ((((ks << 2) + lg) ^ (ra & 7)) << 3));
  };
  auto rdB = [&](const unsigned short* lb, int ni, int ks) -> bf16x8 {
    int rb = wn * 64 + ni * 16 + lr;
    return *reinterpret_cast<const bf16x8*>(lb + rb * 64 + ((((ks << 2) + lg) ^ (rb & 7)) << 3));
  };

  // Prologue: tile0's 4 halves, then tile1's {A1,A2,B2} (B1[1] staged at g=0.ph1).
  stageA(0, 0); stageB(0, 0); stageA(0, 1); stageB(0, 1);
  stageA(1, 0); stageA(1, 1); stageB(1, 1);
  asm volatile("s_waitcnt vmcnt(6)" ::: "memory");   // retire tile0's 4 halves
  __builtin_amdgcn_s_barrier();

  for (int g = 0; g < nt; ++g) {
    const unsigned short* la = lA[g & 1];
    const unsigned short* lb = lB[g & 1];

    // ---- phase 1: A mi0-3 + B ni0-1 (12 reads) | stage B1[g+1] | q0
#pragma unroll
    for (int mi = 0; mi < 4; ++mi) { af[mi][0] = rdA(la, mi, 0); af[mi][1] = rdA(la, mi, 1); }
#pragma unroll
    for (int ni = 0; ni < 2; ++ni) { bfr[ni][0] = rdB(lb, ni, 0); bfr[ni][1] = rdB(lb, ni, 1); }
    if (g + 1 < nt) stageB(g + 1, 0);
    __builtin_amdgcn_s_barrier();
    asm volatile("s_waitcnt lgkmcnt(0)" ::: "memory");
    __builtin_amdgcn_sched_barrier(0);
    __builtin_amdgcn_s_setprio(1);
#pragma unroll
    for (int mi = 0; mi < 4; ++mi)
#pragma unroll
      for (int ni = 0; ni < 2; ++ni) {
        acc[mi][ni] = MFMA16(af[mi][0], bfr[ni][0], acc[mi][ni]);
        acc[mi][ni] = MFMA16(af[mi][1], bfr[ni][1], acc[mi][ni]);
      }
    __builtin_amdgcn_s_setprio(0);
    __builtin_amdgcn_s_barrier();

    // ---- phase 2: A mi4-7 (8 reads) | stage A1[g+2] | q1
#pragma unroll
    for (int mi = 4; mi < 8; ++mi) { af[mi][0] = rdA(la, mi, 0); af[mi][1] = rdA(la, mi, 1); }
    if (g + 2 < nt) stageA(g + 2, 0);
    __builtin_amdgcn_s_barrier();
    asm volatile("s_waitcnt lgkmcnt(0)" ::: "memory");
    __builtin_amdgcn_sched_barrier(0);
    __builtin_amdgcn_s_setprio(1);
#pragma unroll
    for (int mi = 4; mi < 8; ++mi)
#pragma unroll
      for (int ni = 0; ni < 2; ++ni) {
        acc[mi][ni] = MFMA16(af[mi][0], bfr[ni][0], acc[mi][ni]);
        acc[mi][ni] = MFMA16(af[mi][1], bfr[ni][1], acc[mi][ni]);
      }
    __builtin_amdgcn_s_setprio(0);
    __builtin_amdgcn_s_barrier();

    // ---- phase 3: B ni2-3 (4 reads) | stage A2[g+2] | q2
#pragma unroll
    for (int ni = 2; ni < 4; ++ni) { bfr[ni][0] = rdB(lb, ni, 0); bfr[ni][1] = rdB(lb, ni, 1); }
    if (g + 2 < nt) stageA(g + 2, 1);
    __builtin_amdgcn_s_barrier();
    asm volatile("s_waitcnt lgkmcnt(0)" ::: "memory");
    __builtin_amdgcn_sched_barrier(0);
    __builtin_amdgcn_s_setprio(1);
#pragma unroll
    for (int mi = 0; mi < 4; ++mi)
#pragma unroll
      for (int ni = 2; ni < 4; ++ni) {
        acc[mi][ni] = MFMA16(af[mi][0], bfr[ni][0], acc[mi][ni]);
        acc[mi][ni] = MFMA16(af[mi][1], bfr[ni][1], acc[mi][ni]);
      }
    __builtin_amdgcn_s_setprio(0);
    __builtin_amdgcn_s_barrier();

    // ---- phase 4: no reads | stage B2[g+2] | vmcnt(6) | q3
    if (g + 2 < nt) stageB(g + 2, 1);
    asm volatile("s_waitcnt vmcnt(6)" ::: "memory");   // retires tile g+1's 4 halves
    __builtin_amdgcn_s_barrier();
    __builtin_amdgcn_sched_barrier(0);
    __builtin_amdgcn_s_setprio(1);
#pragma unroll
    for (int mi = 4; mi < 8; ++mi)
#pragma unroll
      for (int ni = 2; ni < 4; ++ni) {
        acc[mi][ni] = MFMA16(af[mi][0], bfr[ni][0], acc[mi][ni]);
        acc[mi][ni] = MFMA16(af[mi][1], bfr[ni][1], acc[mi][ni]);
      }
    __builtin_amdgcn_s_setprio(0);
    __builtin_amdgcn_s_barrier();
  }

  // ---------------- epilogue ----------------
#pragma unroll
  for (int mi = 0; mi < 8; ++mi) {
#pragma unroll
    for (int ni = 0; ni < 4; ++ni) {
      int n = tn * 256 + wn * 64 + ni * 16 + lr;
#pragma unroll
      for (int r = 0; r < 4; ++r) {
        int m = tm * 256 + wm * 128 + mi * 16 + lg * 4 + r;
        float v = acc[mi][ni][r];
        if (MODE == 1) {
          v += bias[n];
          int sel = n >> 11;
          int h = (n >> 7) & 15;
          int d = n & 127;
          int b = m >> 11;
          int s = m & 2047;
          if (sel == 0)
            outQ[(((size_t)(b * 16 + h)) * 2048 + s) * 128 + d] = f2bf(v);
          else if (sel == 1)
            outK[(((size_t)(b * 16 + h)) * 2048 + s) * 128 + d] = f2bf(v);
          else
            outV[(((size_t)(b * 16 + h)) * 128 + d) * 2048 + s] = f2bf(v);
        } else {
          outF[(size_t)m * 2048 + n] = v;
        }
      }
    }
  }
}

// ---------------- in-place RoPE on Q,K ----------------

__global__ void rope_inplace(unsigned short* __restrict__ Qr, unsigned short* __restrict__ Kr,
                             const int* __restrict__ pos, const float* __restrict__ tab) {
  int i = blockIdx.x * blockDim.x + threadIdx.x; // 2^20 threads
  if (i >= (1 << 20)) return;
  int jb = i & 7;
  int s  = (i >> 3) & 2047;
  int bh = (i >> 14) & 31;
  int a  = i >> 19;
  unsigned short* base = (a ? Kr : Qr) + (((size_t)bh * 2048 + s) * 128);
  int b = bh >> 4;
  int p = pos[b * 2048 + s];
  bf16x8 x1 = *reinterpret_cast<bf16x8*>(base + jb * 8);
  bf16x8 x2 = *reinterpret_cast<bf16x8*>(base + 64 + jb * 8);
  bf16x8 y1, y2;
#pragma unroll
  for (int t = 0; t < 8; ++t) {
    int j = jb * 8 + t;
    float c  = tab[((size_t)p * 64 + j) * 2];
    float sn = tab[((size_t)p * 64 + j) * 2 + 1];
    float a1 = bf2f((unsigned short)x1[t]);
    float a2 = bf2f((unsigned short)x2[t]);
    y1[t] = (short)f2bf(a1 * c - a2 * sn);
    y2[t] = (short)f2bf(a2 * c + a1 * sn);
  }
  *reinterpret_cast<bf16x8*>(base + jb * 8) = y1;
  *reinterpret_cast<bf16x8*>(base + 64 + jb * 8) = y2;
}

// ---------------- flash attention (causal, work-balanced) ----------------
// Block bx handles q-tiles {31-bx, bx}: every block does exactly 33 K-iters.

__global__ __launch_bounds__(256)
void attn_fwd(const unsigned short* __restrict__ Qr,
              const unsigned short* __restrict__ Kr,
              const unsigned short* __restrict__ Vt,
              unsigned short* __restrict__ attnb) {
  __shared__ unsigned short Ks[64 * 128];
  __shared__ unsigned short Vs[128 * 64];
  __shared__ unsigned short Ps[64 * 64];
  const int bx = blockIdx.x, bh = blockIdx.y;
  const int tid = threadIdx.x;
  const int wid = tid >> 6, lane = tid & 63;
  const int lr = lane & 15, lg = lane >> 4;
  const unsigned short* Qb = Qr + (size_t)bh * SS * HDD;
  const unsigned short* Kb = Kr + (size_t)bh * SS * HDD;
  const unsigned short* Vb = Vt + (size_t)bh * HDD * SS;
  const int b = bh >> 4, h = bh & 15;

#pragma unroll 1
  for (int qi = 0; qi < 2; ++qi) {
    const int qt = qi ? bx : (31 - bx);

    bf16x8 qf[4];
#pragma unroll
    for (int kk = 0; kk < 4; ++kk)
      qf[kk] = *reinterpret_cast<const bf16x8*>(
          Qb + ((size_t)(qt * 64 + wid * 16 + lr)) * 128 + kk * 32 + lg * 8);

    f32x4 oacc[8] = {};
    float mrow[4], lsum[4];
#pragma unroll
    for (int r = 0; r < 4; ++r) { mrow[r] = -1e30f; lsum[r] = 0.f; }

    for (int kt = 0; kt <= qt; ++kt) {
#pragma unroll
      for (int ch = 0; ch < 4; ++ch) {
        int c = tid + ch * 256;
        {
          int row = c >> 4, cb = c & 15;
          gll16(Kb + ((size_t)(kt * 64 + row)) * 128 + ((cb ^ (row & 7)) << 3), Ks + c * 8);
        }
        {
          int row = c >> 3, cb = c & 7;
          gll16(Vb + (size_t)row * SS + kt * 64 + ((cb ^ (row & 7)) << 3), Vs + c * 8);
        }
      }
      __syncthreads();

      float sv[4][4];
#pragma unroll
      for (int nt = 0; nt < 4; ++nt) {
        f32x4 sa = {};
#pragma unroll
        for (int kk = 0; kk < 4; ++kk) {
          int row = nt * 16 + lr;
          bf16x8 kf = *reinterpret_cast<const bf16x8*>(
              Ks + row * 128 + (((kk * 4 + lg) ^ (row & 7)) << 3));
          sa = __builtin_amdgcn_mfma_f32_16x16x32_bf16(qf[kk], kf, sa, 0, 0, 0);
        }
#pragma unroll
        for (int r = 0; r < 4; ++r) {
          float s = sa[r] * 0.088388347648318447f; // 1/sqrt(128)
          if (kt == qt && (nt * 16 + lr) > (wid * 16 + lg * 4 + r)) s -= 1e9f;
          sv[nt][r] = s;
        }
      }

      float tmax[4];
#pragma unroll
      for (int r = 0; r < 4; ++r)
        tmax[r] = fmaxf(fmaxf(sv[0][r], sv[1][r]), fmaxf(sv[2][r], sv[3][r]));
#pragma unroll
      for (int r = 0; r < 4; ++r) {
        tmax[r] = fmaxf(tmax[r], __shfl_xor(tmax[r], 1));
        tmax[r] = fmaxf(tmax[r], __shfl_xor(tmax[r], 2));
        tmax[r] = fmaxf(tmax[r], __shfl_xor(tmax[r], 4));
        tmax[r] = fmaxf(tmax[r], __shfl_xor(tmax[r], 8));
      }
      float fr[4], tsum[4];
#pragma unroll
      for (int r = 0; r < 4; ++r) {
        float mn = fmaxf(mrow[r], tmax[r]);
        fr[r] = __expf(mrow[r] - mn);
        mrow[r] = mn;
        tsum[r] = 0.f;
      }
#pragma unroll
      for (int nt = 0; nt < 4; ++nt) {
        int colc = nt * 2 + (lr >> 3);
#pragma unroll
        for (int r = 0; r < 4; ++r) {
          float p = __expf(sv[nt][r] - mrow[r]);
          tsum[r] += p;
          int row = wid * 16 + lg * 4 + r;
          Ps[row * 64 + ((colc ^ (row & 7)) << 3) + (lr & 7)] = f2bf(p);
        }
      }
#pragma unroll
      for (int r = 0; r < 4; ++r) {
        tsum[r] += __shfl_xor(tsum[r], 1);
        tsum[r] += __shfl_xor(tsum[r], 2);
        tsum[r] += __shfl_xor(tsum[r], 4);
        tsum[r] += __shfl_xor(tsum[r], 8);
        lsum[r] = lsum[r] * fr[r] + tsum[r];
      }
#pragma unroll
      for (int ct = 0; ct < 8; ++ct)
#pragma unroll
        for (int r = 0; r < 4; ++r)
          oacc[ct][r] *= fr[r];

      bf16x8 pf[2];
#pragma unroll
      for (int ks = 0; ks < 2; ++ks) {
        int row = wid * 16 + lr;
        pf[ks] = *reinterpret_cast<const bf16x8*>(
            Ps + row * 64 + (((ks * 4 + lg) ^ (row & 7)) << 3));
      }
#pragma unroll
      for (int ct = 0; ct < 8; ++ct) {
#pragma unroll
        for (int ks = 0; ks < 2; ++ks) {
          int row = ct * 16 + lr;
          bf16x8 vf = *reinterpret_cast<const bf16x8*>(
              Vs + row * 64 + (((ks * 4 + lg) ^ (row & 7)) << 3));
          oacc[ct] = __builtin_amdgcn_mfma_f32_16x16x32_bf16(pf[ks], vf, oacc[ct], 0, 0, 0);
        }
      }
      __syncthreads();
    }

#pragma unroll
    for (int r = 0; r < 4; ++r) {
      float rl = 1.f / lsum[r];
      int qg = qt * 64 + wid * 16 + lg * 4 + r;
#pragma unroll
      for (int ct = 0; ct < 8; ++ct) {
        int d = ct * 16 + lr;
        attnb[((size_t)b * SS + qg) * HH + h * 128 + d] = f2bf(oacc[ct][r] * rl);
      }
    }
  }
}

// ---------------- launch ----------------

extern "C" void kernel_launch(void* const* d_in, const int* in_sizes, int n_in,
                              void* d_out, int out_size, void* d_ws, size_t ws_size,
                              hipStream_t stream) {
  const float* hs     = (const float*)d_in[0];
  const int*   pos    = (const int*)d_in[1];
  const float* qkv_w  = (const float*)d_in[3];
  const float* qkv_b  = (const float*)d_in[4];
  const float* o_w    = (const float*)d_in[5];
  float* out = (float*)d_out;
  char* ws = (char*)d_ws;

  unsigned short* hsb   = (unsigned short*)(ws);                  // 16 MB
  unsigned short* wqkvb = (unsigned short*)(ws + 16777216);       // 24 MB
  unsigned short* owb   = (unsigned short*)(ws + 41943040);       // 8 MB
  unsigned short* Qr    = (unsigned short*)(ws + 50331648);       // 16 MB
  unsigned short* Kr    = (unsigned short*)(ws + 67108864);       // 16 MB
  unsigned short* Vt    = (unsigned short*)(ws + 83886080);       // 16 MB
  unsigned short* attnb = (unsigned short*)(ws + 100663296);      // 16 MB
  float*          tab   = (float*)(ws + 117440512);               // 1 MB

  convert_bf16<<<2097152 / 256, 256, 0, stream>>>(hs, hsb, 2097152);
  convert_bf16<<<3145728 / 256, 256, 0, stream>>>(qkv_w, wqkvb, 3145728);
  convert_bf16<<<1048576 / 256, 256, 0, stream>>>(o_w, owb, 1048576);
  build_tab<<<512, 256, 0, stream>>>(tab);

  gemm8p<1><<<dim3(24, 16), 512, 0, stream>>>(hsb, wqkvb, qkv_b, nullptr, Qr, Kr, Vt, 2048);
  rope_inplace<<<4096, 256, 0, stream>>>(Qr, Kr, pos, tab);
  attn_fwd<<<dim3(16, 32), 256, 0, stream>>>(Qr, Kr, Vt, attnb);
  gemm8p<0><<<dim3(8, 16), 512, 0, stream>>>(attnb, owb, nullptr, out, nullptr, nullptr, nullptr, 2048);
}

// Round 3
// 318.742 us; speedup vs baseline: 1.1821x; 1.0654x over previous
//
#include <hip/hip_runtime.h>
#include <hip/hip_bf16.h>

#define BB 2
#define SS 2048
#define HH 2048
#define NHH 16
#define HDD 128

using f32x4  = __attribute__((ext_vector_type(4))) float;
using bf16x8 = __attribute__((ext_vector_type(8))) short;

__device__ __forceinline__ unsigned short f2bf(float x) {
  unsigned int u = __float_as_uint(x);
  unsigned int r = (u + 0x7FFFu + ((u >> 16) & 1u)) >> 16;
  return (unsigned short)r;
}
__device__ __forceinline__ float bf2f(unsigned short u) {
  return __uint_as_float(((unsigned int)u) << 16);
}

__device__ __forceinline__ void gll16(const void* g, void* l) {
  __builtin_amdgcn_global_load_lds(
      (__attribute__((address_space(1))) void*)(g),
      (__attribute__((address_space(3))) void*)(l), 16, 0, 0);
}

#define MFMA16(a, b, c) __builtin_amdgcn_mfma_f32_16x16x32_bf16(a, b, c, 0, 0, 0)

// ---------------- converts + rope table ----------------

__global__ void convert_bf16(const float* __restrict__ in, unsigned short* __restrict__ out, int n4) {
  int i = blockIdx.x * blockDim.x + threadIdx.x;
  if (i >= n4) return;
  float4 v = reinterpret_cast<const float4*>(in)[i];
  ushort4 o;
  o.x = f2bf(v.x); o.y = f2bf(v.y); o.z = f2bf(v.z); o.w = f2bf(v.w);
  reinterpret_cast<ushort4*>(out)[i] = o;
}

__global__ void build_tab(float* __restrict__ tab) { // [S][64][2] = cos,sin
  int i = blockIdx.x * blockDim.x + threadIdx.x;
  if (i >= SS * 64) return;
  int s = i >> 6, j = i & 63;
  float invf = expf(-logf(10000.f) * ((float)j / 64.f));
  float a = (float)s * invf;
  tab[i * 2]     = cosf(a);
  tab[i * 2 + 1] = sinf(a);
}

// ---------- cross-slot pipelined bt-GEMM (1 barrier per K-tile) ----------
// C[M,N] = A[M,K] * W[N,K]^T. 512 threads = 8 waves (2M x 4N).
// BM = 32*MI (256 or 128), BN = 256, BK = 64, 2-slot LDS double buffer.
// 4 slots per K-tile g; each slot issues NEXT slot's ds_reads, waits only a
// COUNTED lgkmcnt for the prior slot's reads, then runs its MFMA quadrant:
//   P0: read bfr23[g]      | lgkm(4)  | mfma af03 x bfr01
//   P1: read af47[g]       | lgkm(MI) | mfma af03 x bfr23
//   P2: vmcnt(0)+lgkm(0); s_barrier; read af03[g+1]; stage A[g+2] | mfma af47 x bfr01
//   P3: read bfr01[g+1]; stage B[g+2]                             | mfma af47 x bfr23
// Between barrier(g) and barrier(g+1): all ds_reads hit slot (g+1)&1, all
// stages write slot g&1 -> disjoint, so ONE barrier per tile is race-free.
// Fragments are single-buffered (each set is dead one slot before refill).
// Swizzle: 16B chunk c stored at c ^ (row&7) (pre-swizzled global source,
// matched on ds_read) -> conflict-free.

template<int MODE, int MI>
__global__ __launch_bounds__(512, 1)
void gemm_pipe(const unsigned short* __restrict__ A,
               const unsigned short* __restrict__ Bw,
               const float* __restrict__ bias,
               float* __restrict__ outF,
               unsigned short* __restrict__ outQ,
               unsigned short* __restrict__ outK,
               unsigned short* __restrict__ outV,
               int Kdim) {
  constexpr int BM = 32 * MI;                 // 256 (MI=8) or 128 (MI=4)
  __shared__ unsigned short lA[2][BM * 64];
  __shared__ unsigned short lB[2][256 * 64];
  const int tid = threadIdx.x;
  const int tn = blockIdx.x, tm = blockIdx.y;
  const int wid = tid >> 6, lane = tid & 63;
  const int wm = wid >> 2, wn = wid & 3;      // 2 x 4 wave grid
  const int lr = lane & 15, lg = lane >> 4;

  const unsigned short* Ab = A + (size_t)tm * BM * Kdim;
  const unsigned short* Bb = Bw + (size_t)tn * 256 * Kdim;

  f32x4 acc[MI][4] = {};
  bf16x8 af[MI][2], bfr[4][2];

  const int nt = Kdim >> 6;

  // ---- staging: A-half h rows = {wm_part*16MI + h*8MI + s}, B-half h rows =
  // {wn_part*64 + h*32 + s}. These are exactly the row-sets consumed by the
  // matching fragment half.
  auto stageA = [&](int t, int h) {
    unsigned short* L = lA[t & 1];
    const int k0 = t << 6;
#pragma unroll
    for (int p = 0; p < BM / 128; ++p) {
      int cl = p * 512 + tid;
      int ri = cl >> 3, c = cl & 7;
      int row = (ri / (8 * MI)) * (16 * MI) + h * (8 * MI) + (ri % (8 * MI));
      int cg = c ^ (row & 7);
      gll16(Ab + (size_t)row * Kdim + k0 + (cg << 3), L + row * 64 + (c << 3));
    }
  };
  auto stageB = [&](int t, int h) {
    unsigned short* L = lB[t & 1];
    const int k0 = t << 6;
#pragma unroll
    for (int p = 0; p < 2; ++p) {
      int cl = p * 512 + tid;
      int ri = cl >> 3, c = cl & 7;
      int row = (ri >> 5 << 6) + (h << 5) + (ri & 31);
      int cg = c ^ (row & 7);
      gll16(Bb + (size_t)row * Kdim + k0 + (cg << 3), L + row * 64 + (c << 3));
    }
  };
  auto readAhalf = [&](int g, int h) {
    const unsigned short* la = lA[g & 1];
#pragma unroll
    for (int mi = h * (MI / 2); mi < (h + 1) * (MI / 2); ++mi) {
      int ra = wm * (BM / 2) + mi * 16 + lr;
      af[mi][0] = *reinterpret_cast<const bf16x8*>(la + ra * 64 + ((lg ^ (ra & 7)) << 3));
      af[mi][1] = *reinterpret_cast<const bf16x8*>(la + ra * 64 + (((4 + lg) ^ (ra & 7)) << 3));
    }
  };
  auto readBhalf = [&](int g, int h) {
    const unsigned short* lb = lB[g & 1];
#pragma unroll
    for (int ni = h * 2; ni < h * 2 + 2; ++ni) {
      int rb = wn * 64 + ni * 16 + lr;
      bfr[ni][0] = *reinterpret_cast<const bf16x8*>(lb + rb * 64 + ((lg ^ (rb & 7)) << 3));
      bfr[ni][1] = *reinterpret_cast<const bf16x8*>(lb + rb * 64 + (((4 + lg) ^ (rb & 7)) << 3));
    }
  };
  auto quad = [&](int ah, int bh) {
    __builtin_amdgcn_s_setprio(1);
#pragma unroll
    for (int mi = ah * (MI / 2); mi < (ah + 1) * (MI / 2); ++mi)
#pragma unroll
      for (int ni = bh * 2; ni < bh * 2 + 2; ++ni) {
        acc[mi][ni] = MFMA16(af[mi][0], bfr[ni][0], acc[mi][ni]);
        acc[mi][ni] = MFMA16(af[mi][1], bfr[ni][1], acc[mi][ni]);
      }
    __builtin_amdgcn_s_setprio(0);
  };

  // ---- prologue: stage tiles 0 and 1; retire tile 0; preload its frags.
  stageA(0, 0); stageA(0, 1); stageB(0, 0); stageB(0, 1);
  stageA(1, 0); stageA(1, 1); stageB(1, 0); stageB(1, 1);
  if constexpr (MI == 8) asm volatile("s_waitcnt vmcnt(8)" ::: "memory");
  else                   asm volatile("s_waitcnt vmcnt(6)" ::: "memory");
  __builtin_amdgcn_s_barrier();
  __builtin_amdgcn_sched_barrier(0);
  readAhalf(0, 0);          // af03[0]
  readBhalf(0, 0);          // bfr01[0]

  for (int g = 0; g < nt; ++g) {
    // ---- P0: prefetch bfr23[g]; compute af03 x bfr01
    readBhalf(g, 1);
    asm volatile("s_waitcnt lgkmcnt(4)" ::: "memory");   // drain af03[g], bfr01[g]
    __builtin_amdgcn_sched_barrier(0);
    quad(0, 0);

    // ---- P1: prefetch af47[g]; compute af03 x bfr23
    readAhalf(g, 1);
    if constexpr (MI == 8) asm volatile("s_waitcnt lgkmcnt(8)" ::: "memory"); // drain bfr23[g]
    else                   asm volatile("s_waitcnt lgkmcnt(4)" ::: "memory");
    __builtin_amdgcn_sched_barrier(0);
    quad(0, 1);

    // ---- P2: tile boundary. vmcnt(0) retires tile g+1's staging; lgkm(0)
    // finishes af47[g]; barrier separates all waves' reads of slot g&1 from
    // the upcoming stages into slot g&1.
    asm volatile("s_waitcnt vmcnt(0) lgkmcnt(0)" ::: "memory");
    __builtin_amdgcn_s_barrier();
    __builtin_amdgcn_sched_barrier(0);
    if (g + 1 < nt) readAhalf(g + 1, 0);                 // af03[g+1], slot (g+1)&1
    if (g + 2 < nt) { stageA(g + 2, 0); stageA(g + 2, 1); }  // slot g&1
    quad(1, 0);

    // ---- P3: prefetch bfr01[g+1]; stage B[g+2]; compute af47 x bfr23
    if (g + 1 < nt) readBhalf(g + 1, 0);                 // slot (g+1)&1
    if (g + 2 < nt) { stageB(g + 2, 0); stageB(g + 2, 1); }  // slot g&1
    quad(1, 1);
  }

  // ---------------- epilogue ----------------
#pragma unroll
  for (int mi = 0; mi < MI; ++mi) {
#pragma unroll
    for (int ni = 0; ni < 4; ++ni) {
      int n = tn * 256 + wn * 64 + ni * 16 + lr;
#pragma unroll
      for (int r = 0; r < 4; ++r) {
        int m = tm * BM + wm * (BM / 2) + mi * 16 + lg * 4 + r;
        float v = acc[mi][ni][r];
        if (MODE == 1) {
          v += bias[n];
          int sel = n >> 11;
          int h = (n >> 7) & 15;
          int d = n & 127;
          int b = m >> 11;
          int s = m & 2047;
          if (sel == 0)
            outQ[(((size_t)(b * 16 + h)) * 2048 + s) * 128 + d] = f2bf(v);
          else if (sel == 1)
            outK[(((size_t)(b * 16 + h)) * 2048 + s) * 128 + d] = f2bf(v);
          else
            outV[(((size_t)(b * 16 + h)) * 128 + d) * 2048 + s] = f2bf(v);
        } else {
          outF[(size_t)m * 2048 + n] = v;
        }
      }
    }
  }
}

// ---------------- in-place RoPE on Q,K ----------------

__global__ void rope_inplace(unsigned short* __restrict__ Qr, unsigned short* __restrict__ Kr,
                             const int* __restrict__ pos, const float* __restrict__ tab) {
  int i = blockIdx.x * blockDim.x + threadIdx.x; // 2^20 threads
  if (i >= (1 << 20)) return;
  int jb = i & 7;
  int s  = (i >> 3) & 2047;
  int bh = (i >> 14) & 31;
  int a  = i >> 19;
  unsigned short* base = (a ? Kr : Qr) + (((size_t)bh * 2048 + s) * 128);
  int b = bh >> 4;
  int p = pos[b * 2048 + s];
  bf16x8 x1 = *reinterpret_cast<bf16x8*>(base + jb * 8);
  bf16x8 x2 = *reinterpret_cast<bf16x8*>(base + 64 + jb * 8);
  bf16x8 y1, y2;
#pragma unroll
  for (int t = 0; t < 8; ++t) {
    int j = jb * 8 + t;
    float c  = tab[((size_t)p * 64 + j) * 2];
    float sn = tab[((size_t)p * 64 + j) * 2 + 1];
    float a1 = bf2f((unsigned short)x1[t]);
    float a2 = bf2f((unsigned short)x2[t]);
    y1[t] = (short)f2bf(a1 * c - a2 * sn);
    y2[t] = (short)f2bf(a2 * c + a1 * sn);
  }
  *reinterpret_cast<bf16x8*>(base + jb * 8) = y1;
  *reinterpret_cast<bf16x8*>(base + 64 + jb * 8) = y2;
}

// ---------------- flash attention (causal, work-balanced) ----------------
// Block bx handles q-tiles {31-bx, bx}: every block does exactly 33 K-iters.

__global__ __launch_bounds__(256)
void attn_fwd(const unsigned short* __restrict__ Qr,
              const unsigned short* __restrict__ Kr,
              const unsigned short* __restrict__ Vt,
              unsigned short* __restrict__ attnb) {
  __shared__ unsigned short Ks[64 * 128];
  __shared__ unsigned short Vs[128 * 64];
  __shared__ unsigned short Ps[64 * 64];
  const int bx = blockIdx.x, bh = blockIdx.y;
  const int tid = threadIdx.x;
  const int wid = tid >> 6, lane = tid & 63;
  const int lr = lane & 15, lg = lane >> 4;
  const unsigned short* Qb = Qr + (size_t)bh * SS * HDD;
  const unsigned short* Kb = Kr + (size_t)bh * SS * HDD;
  const unsigned short* Vb = Vt + (size_t)bh * HDD * SS;
  const int b = bh >> 4, h = bh & 15;

#pragma unroll 1
  for (int qi = 0; qi < 2; ++qi) {
    const int qt = qi ? bx : (31 - bx);

    bf16x8 qf[4];
#pragma unroll
    for (int kk = 0; kk < 4; ++kk)
      qf[kk] = *reinterpret_cast<const bf16x8*>(
          Qb + ((size_t)(qt * 64 + wid * 16 + lr)) * 128 + kk * 32 + lg * 8);

    f32x4 oacc[8] = {};
    float mrow[4], lsum[4];
#pragma unroll
    for (int r = 0; r < 4; ++r) { mrow[r] = -1e30f; lsum[r] = 0.f; }

    for (int kt = 0; kt <= qt; ++kt) {
#pragma unroll
      for (int ch = 0; ch < 4; ++ch) {
        int c = tid + ch * 256;
        {
          int row = c >> 4, cb = c & 15;
          gll16(Kb + ((size_t)(kt * 64 + row)) * 128 + ((cb ^ (row & 7)) << 3), Ks + c * 8);
        }
        {
          int row = c >> 3, cb = c & 7;
          gll16(Vb + (size_t)row * SS + kt * 64 + ((cb ^ (row & 7)) << 3), Vs + c * 8);
        }
      }
      __syncthreads();

      float sv[4][4];
#pragma unroll
      for (int nt = 0; nt < 4; ++nt) {
        f32x4 sa = {};
#pragma unroll
        for (int kk = 0; kk < 4; ++kk) {
          int row = nt * 16 + lr;
          bf16x8 kf = *reinterpret_cast<const bf16x8*>(
              Ks + row * 128 + (((kk * 4 + lg) ^ (row & 7)) << 3));
          sa = __builtin_amdgcn_mfma_f32_16x16x32_bf16(qf[kk], kf, sa, 0, 0, 0);
        }
#pragma unroll
        for (int r = 0; r < 4; ++r) {
          float s = sa[r] * 0.088388347648318447f; // 1/sqrt(128)
          if (kt == qt && (nt * 16 + lr) > (wid * 16 + lg * 4 + r)) s -= 1e9f;
          sv[nt][r] = s;
        }
      }

      float tmax[4];
#pragma unroll
      for (int r = 0; r < 4; ++r)
        tmax[r] = fmaxf(fmaxf(sv[0][r], sv[1][r]), fmaxf(sv[2][r], sv[3][r]));
#pragma unroll
      for (int r = 0; r < 4; ++r) {
        tmax[r] = fmaxf(tmax[r], __shfl_xor(tmax[r], 1));
        tmax[r] = fmaxf(tmax[r], __shfl_xor(tmax[r], 2));
        tmax[r] = fmaxf(tmax[r], __shfl_xor(tmax[r], 4));
        tmax[r] = fmaxf(tmax[r], __shfl_xor(tmax[r], 8));
      }
      float fr[4], tsum[4];
#pragma unroll
      for (int r = 0; r < 4; ++r) {
        float mn = fmaxf(mrow[r], tmax[r]);
        fr[r] = __expf(mrow[r] - mn);
        mrow[r] = mn;
        tsum[r] = 0.f;
      }
#pragma unroll
      for (int nt = 0; nt < 4; ++nt) {
        int colc = nt * 2 + (lr >> 3);
#pragma unroll
        for (int r = 0; r < 4; ++r) {
          float p = __expf(sv[nt][r] - mrow[r]);
          tsum[r] += p;
          int row = wid * 16 + lg * 4 + r;
          Ps[row * 64 + ((colc ^ (row & 7)) << 3) + (lr & 7)] = f2bf(p);
        }
      }
#pragma unroll
      for (int r = 0; r < 4; ++r) {
        tsum[r] += __shfl_xor(tsum[r], 1);
        tsum[r] += __shfl_xor(tsum[r], 2);
        tsum[r] += __shfl_xor(tsum[r], 4);
        tsum[r] += __shfl_xor(tsum[r], 8);
        lsum[r] = lsum[r] * fr[r] + tsum[r];
      }
#pragma unroll
      for (int ct = 0; ct < 8; ++ct)
#pragma unroll
        for (int r = 0; r < 4; ++r)
          oacc[ct][r] *= fr[r];

      bf16x8 pf[2];
#pragma unroll
      for (int ks = 0; ks < 2; ++ks) {
        int row = wid * 16 + lr;
        pf[ks] = *reinterpret_cast<const bf16x8*>(
            Ps + row * 64 + (((ks * 4 + lg) ^ (row & 7)) << 3));
      }
#pragma unroll
      for (int ct = 0; ct < 8; ++ct) {
#pragma unroll
        for (int ks = 0; ks < 2; ++ks) {
          int row = ct * 16 + lr;
          bf16x8 vf = *reinterpret_cast<const bf16x8*>(
              Vs + row * 64 + (((ks * 4 + lg) ^ (row & 7)) << 3));
          oacc[ct] = __builtin_amdgcn_mfma_f32_16x16x32_bf16(pf[ks], vf, oacc[ct], 0, 0, 0);
        }
      }
      __syncthreads();
    }

#pragma unroll
    for (int r = 0; r < 4; ++r) {
      float rl = 1.f / lsum[r];
      int qg = qt * 64 + wid * 16 + lg * 4 + r;
#pragma unroll
      for (int ct = 0; ct < 8; ++ct) {
        int d = ct * 16 + lr;
        attnb[((size_t)b * SS + qg) * HH + h * 128 + d] = f2bf(oacc[ct][r] * rl);
      }
    }
  }
}

// ---------------- launch ----------------

extern "C" void kernel_launch(void* const* d_in, const int* in_sizes, int n_in,
                              void* d_out, int out_size, void* d_ws, size_t ws_size,
                              hipStream_t stream) {
  const float* hs     = (const float*)d_in[0];
  const int*   pos    = (const int*)d_in[1];
  const float* qkv_w  = (const float*)d_in[3];
  const float* qkv_b  = (const float*)d_in[4];
  const float* o_w    = (const float*)d_in[5];
  float* out = (float*)d_out;
  char* ws = (char*)d_ws;

  unsigned short* hsb   = (unsigned short*)(ws);                  // 16 MB
  unsigned short* wqkvb = (unsigned short*)(ws + 16777216);       // 24 MB
  unsigned short* owb   = (unsigned short*)(ws + 41943040);       // 8 MB
  unsigned short* Qr    = (unsigned short*)(ws + 50331648);       // 16 MB
  unsigned short* Kr    = (unsigned short*)(ws + 67108864);       // 16 MB
  unsigned short* Vt    = (unsigned short*)(ws + 83886080);       // 16 MB
  unsigned short* attnb = (unsigned short*)(ws + 100663296);      // 16 MB
  float*          tab   = (float*)(ws + 117440512);               // 1 MB

  convert_bf16<<<2097152 / 256, 256, 0, stream>>>(hs, hsb, 2097152);
  convert_bf16<<<3145728 / 256, 256, 0, stream>>>(qkv_w, wqkvb, 3145728);
  convert_bf16<<<1048576 / 256, 256, 0, stream>>>(o_w, owb, 1048576);
  build_tab<<<512, 256, 0, stream>>>(tab);

  gemm_pipe<1, 8><<<dim3(24, 16), 512, 0, stream>>>(hsb, wqkvb, qkv_b, nullptr, Qr, Kr, Vt, 2048);
  rope_inplace<<<4096, 256, 0, stream>>>(Qr, Kr, pos, tab);
  attn_fwd<<<dim3(16, 32), 256, 0, stream>>>(Qr, Kr, Vt, attnb);
  gemm_pipe<0, 4><<<dim3(8, 32), 512, 0, stream>>>(attnb, owb, nullptr, out, nullptr, nullptr, nullptr, 2048);
}

// Round 5
// 318.144 us; speedup vs baseline: 1.1843x; 1.0019x over previous
//
#include <hip/hip_runtime.h>
#include <hip/hip_bf16.h>

#define BB 2
#define SS 2048
#define HH 2048
#define NHH 16
#define HDD 128

using f32x4  = __attribute__((ext_vector_type(4))) float;
using bf16x8 = __attribute__((ext_vector_type(8))) short;

__device__ __forceinline__ unsigned short f2bf(float x) {
  unsigned int u = __float_as_uint(x);
  unsigned int r = (u + 0x7FFFu + ((u >> 16) & 1u)) >> 16;
  return (unsigned short)r;
}
__device__ __forceinline__ float bf2f(unsigned short u) {
  return __uint_as_float(((unsigned int)u) << 16);
}

__device__ __forceinline__ void gll16(const void* g, void* l) {
  __builtin_amdgcn_global_load_lds(
      (__attribute__((address_space(1))) void*)(g),
      (__attribute__((address_space(3))) void*)(l), 16, 0, 0);
}

#define MFMA16(a, b, c) __builtin_amdgcn_mfma_f32_16x16x32_bf16(a, b, c, 0, 0, 0)

template<int N> __device__ __forceinline__ void wlgkm() {
  static_assert(N == 0 || N == 2 || N == 4 || N == 6 || N == 8 || N == 10 || N == 12,
                "unsupported lgkmcnt");
  if constexpr (N == 0)       asm volatile("s_waitcnt lgkmcnt(0)"  ::: "memory");
  else if constexpr (N == 2)  asm volatile("s_waitcnt lgkmcnt(2)"  ::: "memory");
  else if constexpr (N == 4)  asm volatile("s_waitcnt lgkmcnt(4)"  ::: "memory");
  else if constexpr (N == 6)  asm volatile("s_waitcnt lgkmcnt(6)"  ::: "memory");
  else if constexpr (N == 8)  asm volatile("s_waitcnt lgkmcnt(8)"  ::: "memory");
  else if constexpr (N == 10) asm volatile("s_waitcnt lgkmcnt(10)" ::: "memory");
  else if constexpr (N == 12) asm volatile("s_waitcnt lgkmcnt(12)" ::: "memory");
}
template<int N> __device__ __forceinline__ void wvm() {
  static_assert(N == 0 || N == 5 || N == 6 || N == 7 || N == 8, "unsupported vmcnt");
  if constexpr (N == 0)      asm volatile("s_waitcnt vmcnt(0)" ::: "memory");
  else if constexpr (N == 5) asm volatile("s_waitcnt vmcnt(5)" ::: "memory");
  else if constexpr (N == 6) asm volatile("s_waitcnt vmcnt(6)" ::: "memory");
  else if constexpr (N == 7) asm volatile("s_waitcnt vmcnt(7)" ::: "memory");
  else if constexpr (N == 8) asm volatile("s_waitcnt vmcnt(8)" ::: "memory");
}

// ---------------- converts + rope table ----------------

__global__ void convert_bf16(const float* __restrict__ in, unsigned short* __restrict__ out, int n4) {
  int i = blockIdx.x * blockDim.x + threadIdx.x;
  if (i >= n4) return;
  float4 v = reinterpret_cast<const float4*>(in)[i];
  ushort4 o;
  o.x = f2bf(v.x); o.y = f2bf(v.y); o.z = f2bf(v.z); o.w = f2bf(v.w);
  reinterpret_cast<ushort4*>(out)[i] = o;
}

__global__ void build_tab(float* __restrict__ tab) { // [S][64][2] = cos,sin
  int i = blockIdx.x * blockDim.x + threadIdx.x;
  if (i >= SS * 64) return;
  int s = i >> 6, j = i & 63;
  float invf = expf(-logf(10000.f) * ((float)j / 64.f));
  float a = (float)s * invf;
  tab[i * 2]     = cosf(a);
  tab[i * 2 + 1] = sinf(a);
}

// ---------- cross-slot pipelined bt-GEMM (1 barrier per K-tile) ----------
// C[M,N] = A[M,K] * W[N,K]^T. 512 threads = 8 waves (2M x 4N).
// BM = 32*MI, BN = 64*NB, BK = 64, 2-slot LDS double buffer.
// 2*NB slots per K-tile g; each slot prefetches later fragments, waits a
// COUNTED lgkmcnt for its own operands, runs an 8-MFMA quadrant.
// Between barrier(g) and barrier(g+1): all ds_reads hit slot (g+1)&1, all
// stages write slot g&1 -> disjoint -> ONE barrier per tile is race-free.
// Prologue retire count = per-tile vmem ops = 2*(BM/128) + NB (COMPUTED —
// round-4 bug: hardcoded 4+NB was wrong for BM=128 and raced tile0's B).
// Swizzle: 16B chunk c stored at c ^ (row&7) (pre-swizzled global source,
// matched on ds_read) -> conflict-free.

template<int MODE, int MI, int NB>
__global__ __launch_bounds__(512, 1)
void gemm_pipe(const unsigned short* __restrict__ A,
               const unsigned short* __restrict__ Bw,
               const float* __restrict__ bias,
               float* __restrict__ outF,
               unsigned short* __restrict__ outQ,
               unsigned short* __restrict__ outK,
               unsigned short* __restrict__ outV,
               int Kdim) {
  constexpr int BM = 32 * MI;
  constexpr int BN = 64 * NB;
  constexpr int TOPS = 2 * (BM / 128) + NB;   // vmem ops staged per K-tile
  __shared__ unsigned short lA[2][BM * 64];
  __shared__ unsigned short lB[2][BN * 64];
  const int tid = threadIdx.x;
  const int tn = blockIdx.x, tm = blockIdx.y;
  const int wid = tid >> 6, lane = tid & 63;
  const int wm = wid >> 2, wn = wid & 3;      // 2 x 4 wave grid
  const int lr = lane & 15, lg = lane >> 4;

  const unsigned short* Ab = A + (size_t)tm * BM * Kdim;
  const unsigned short* Bb = Bw + (size_t)tn * BN * Kdim;

  f32x4 acc[MI][NB] = {};
  bf16x8 af[MI][2], bfr[NB][2];

  const int nt = Kdim >> 6;

  auto stageA = [&](int t, int h) {          // half-tile: BM/2 rows
    unsigned short* L = lA[t & 1];
    const int k0 = t << 6;
#pragma unroll
    for (int p = 0; p < BM / 128; ++p) {
      int cl = p * 512 + tid;
      int ri = cl >> 3, c = cl & 7;
      int row = (ri / (8 * MI)) * (16 * MI) + h * (8 * MI) + (ri % (8 * MI));
      int cg = c ^ (row & 7);
      gll16(Ab + (size_t)row * Kdim + k0 + (cg << 3), L + row * 64 + (c << 3));
    }
  };
  auto stageB = [&](int t, int h) {          // 1/NB-tile: 64 rows (4 wn x 16)
    unsigned short* L = lB[t & 1];
    const int k0 = t << 6;
    int cl = tid;
    int ri = cl >> 3, c = cl & 7;
    int row = (ri >> 4) * (16 * NB) + h * 16 + (ri & 15);
    int cg = c ^ (row & 7);
    gll16(Bb + (size_t)row * Kdim + k0 + (cg << 3), L + row * 64 + (c << 3));
  };
  auto readAhalf = [&](int g, int h) {       // MI ds_reads
    const unsigned short* la = lA[g & 1];
#pragma unroll
    for (int mi = h * (MI / 2); mi < (h + 1) * (MI / 2); ++mi) {
      int ra = wm * (BM / 2) + mi * 16 + lr;
      af[mi][0] = *reinterpret_cast<const bf16x8*>(la + ra * 64 + ((lg ^ (ra & 7)) << 3));
      af[mi][1] = *reinterpret_cast<const bf16x8*>(la + ra * 64 + (((4 + lg) ^ (ra & 7)) << 3));
    }
  };
  auto readB = [&](int g, int ni) {          // 2 ds_reads
    const unsigned short* lb = lB[g & 1];
    int rb = wn * (16 * NB) + ni * 16 + lr;
    bfr[ni][0] = *reinterpret_cast<const bf16x8*>(lb + rb * 64 + ((lg ^ (rb & 7)) << 3));
    bfr[ni][1] = *reinterpret_cast<const bf16x8*>(lb + rb * 64 + (((4 + lg) ^ (rb & 7)) << 3));
  };
  auto quad = [&](int ah, int ni) {          // 8 MFMA
    __builtin_amdgcn_s_setprio(1);
#pragma unroll
    for (int mi = ah * (MI / 2); mi < (ah + 1) * (MI / 2); ++mi) {
      acc[mi][ni] = MFMA16(af[mi][0], bfr[ni][0], acc[mi][ni]);
      acc[mi][ni] = MFMA16(af[mi][1], bfr[ni][1], acc[mi][ni]);
    }
    __builtin_amdgcn_s_setprio(0);
  };

  // ---- prologue: stage tiles 0 and 1; retire tile 0; preload its frags.
  stageA(0, 0); stageA(0, 1);
#pragma unroll
  for (int h = 0; h < NB; ++h) stageB(0, h);
  stageA(1, 0); stageA(1, 1);
#pragma unroll
  for (int h = 0; h < NB; ++h) stageB(1, h);
  wvm<TOPS>();                                // retire ALL of tile 0's stages
  __builtin_amdgcn_s_barrier();
  __builtin_amdgcn_sched_barrier(0);
  readAhalf(0, 0);
#pragma unroll
  for (int ni = 0; ni < NB - 1; ++ni) readB(0, ni);

  for (int g = 0; g < nt; ++g) {
    // ---- a0 x n0: prefetch last B group of this tile
    readB(g, NB - 1);
    wlgkm<2 * (NB - 1)>();                    // drain af03(g)+bfr0(g)
    __builtin_amdgcn_sched_barrier(0);
    quad(0, 0);

    // ---- a0 x n1: prefetch af47(g)
    readAhalf(g, 1);
    wlgkm<2 * (NB - 2) + MI>();               // drain bfr1(g)
    __builtin_amdgcn_sched_barrier(0);
    quad(0, 1);

    if constexpr (NB == 4) {
      wlgkm<2 + MI>();                        // drain bfr2(g)
      __builtin_amdgcn_sched_barrier(0);
      quad(0, 2);
    }

    // ---- a0 x n(NB-1)
    wlgkm<MI>();                              // drain bfr[NB-1](g)
    __builtin_amdgcn_sched_barrier(0);
    quad(0, NB - 1);

    // ---- a1 x n0: tile boundary (single barrier per tile)
    asm volatile("s_waitcnt vmcnt(0) lgkmcnt(0)" ::: "memory");
    __builtin_amdgcn_s_barrier();
    __builtin_amdgcn_sched_barrier(0);
    if (g + 1 < nt) readAhalf(g + 1, 0);                   // slot (g+1)&1
    if (g + 2 < nt) { stageA(g + 2, 0); stageA(g + 2, 1); } // slot g&1
    quad(1, 0);

    // ---- a1 x n1: stage all B(g+2)
    if (g + 1 < nt) readB(g + 1, 0);
    if (g + 2 < nt) {
#pragma unroll
      for (int h = 0; h < NB; ++h) stageB(g + 2, h);
    }
    quad(1, 1);

    // ---- a1 x nj, j >= 2
    if (g + 1 < nt) readB(g + 1, 1);
    quad(1, 2);
    if constexpr (NB == 4) {
      if (g + 1 < nt) readB(g + 1, 2);
      quad(1, 3);
    }
  }

  // ---------------- epilogue ----------------
#pragma unroll
  for (int mi = 0; mi < MI; ++mi) {
#pragma unroll
    for (int ni = 0; ni < NB; ++ni) {
      int n = tn * BN + wn * (16 * NB) + ni * 16 + lr;
#pragma unroll
      for (int r = 0; r < 4; ++r) {
        int m = tm * BM + wm * (BM / 2) + mi * 16 + lg * 4 + r;
        float v = acc[mi][ni][r];
        if (MODE == 1) {
          v += bias[n];
          int sel = n >> 11;
          int h = (n >> 7) & 15;
          int d = n & 127;
          int b = m >> 11;
          int s = m & 2047;
          if (sel == 0)
            outQ[(((size_t)(b * 16 + h)) * 2048 + s) * 128 + d] = f2bf(v);
          else if (sel == 1)
            outK[(((size_t)(b * 16 + h)) * 2048 + s) * 128 + d] = f2bf(v);
          else
            outV[(((size_t)(b * 16 + h)) * 128 + d) * 2048 + s] = f2bf(v);
        } else {
          outF[(size_t)m * 2048 + n] = v;
        }
      }
    }
  }
}

// ---------------- in-place RoPE on Q,K ----------------

__global__ void rope_inplace(unsigned short* __restrict__ Qr, unsigned short* __restrict__ Kr,
                             const int* __restrict__ pos, const float* __restrict__ tab) {
  int i = blockIdx.x * blockDim.x + threadIdx.x; // 2^20 threads
  if (i >= (1 << 20)) return;
  int jb = i & 7;
  int s  = (i >> 3) & 2047;
  int bh = (i >> 14) & 31;
  int a  = i >> 19;
  unsigned short* base = (a ? Kr : Qr) + (((size_t)bh * 2048 + s) * 128);
  int b = bh >> 4;
  int p = pos[b * 2048 + s];
  bf16x8 x1 = *reinterpret_cast<bf16x8*>(base + jb * 8);
  bf16x8 x2 = *reinterpret_cast<bf16x8*>(base + 64 + jb * 8);
  bf16x8 y1, y2;
#pragma unroll
  for (int t = 0; t < 8; ++t) {
    int j = jb * 8 + t;
    float c  = tab[((size_t)p * 64 + j) * 2];
    float sn = tab[((size_t)p * 64 + j) * 2 + 1];
    float a1 = bf2f((unsigned short)x1[t]);
    float a2 = bf2f((unsigned short)x2[t]);
    y1[t] = (short)f2bf(a1 * c - a2 * sn);
    y2[t] = (short)f2bf(a2 * c + a1 * sn);
  }
  *reinterpret_cast<bf16x8*>(base + jb * 8) = y1;
  *reinterpret_cast<bf16x8*>(base + 64 + jb * 8) = y2;
}

// ---------------- flash attention (causal, work-balanced) ----------------
// Block bx handles q-tiles {31-bx, bx}: every block does exactly 33 K-iters.
// K/V double-buffered; stage(kt+1) issued before compute(kt); counted
// vmcnt(8) retires exactly stage(kt); raw s_barrier (no full drain).

__global__ __launch_bounds__(256)
void attn_fwd(const unsigned short* __restrict__ Qr,
              const unsigned short* __restrict__ Kr,
              const unsigned short* __restrict__ Vt,
              unsigned short* __restrict__ attnb) {
  __shared__ unsigned short Ks[2][64 * 128];
  __shared__ unsigned short Vs[2][128 * 64];
  __shared__ unsigned short Ps[64 * 64];
  const int bx = blockIdx.x, bh = blockIdx.y;
  const int tid = threadIdx.x;
  const int wid = tid >> 6, lane = tid & 63;
  const int lr = lane & 15, lg = lane >> 4;
  const unsigned short* Qb = Qr + (size_t)bh * SS * HDD;
  const unsigned short* Kb = Kr + (size_t)bh * SS * HDD;
  const unsigned short* Vb = Vt + (size_t)bh * HDD * SS;
  const int b = bh >> 4, h = bh & 15;

  auto stage = [&](int kt, int buf) {        // 8 gll per thread
#pragma unroll
    for (int ch = 0; ch < 4; ++ch) {
      int c = tid + ch * 256;
      {
        int row = c >> 4, cb = c & 15;
        gll16(Kb + ((size_t)(kt * 64 + row)) * 128 + ((cb ^ (row & 7)) << 3), Ks[buf] + c * 8);
      }
      {
        int row = c >> 3, cb = c & 7;
        gll16(Vb + (size_t)row * SS + kt * 64 + ((cb ^ (row & 7)) << 3), Vs[buf] + c * 8);
      }
    }
  };

#pragma unroll 1
  for (int qi = 0; qi < 2; ++qi) {
    const int qt = qi ? bx : (31 - bx);

    bf16x8 qf[4];
#pragma unroll
    for (int kk = 0; kk < 4; ++kk)
      qf[kk] = *reinterpret_cast<const bf16x8*>(
          Qb + ((size_t)(qt * 64 + wid * 16 + lr)) * 128 + kk * 32 + lg * 8);

    f32x4 oacc[8] = {};
    float mrow[4], lsum[4];
#pragma unroll
    for (int r = 0; r < 4; ++r) { mrow[r] = -1e30f; lsum[r] = 0.f; }

    int cur = 0;
    stage(0, 0);

#pragma unroll 1
    for (int kt = 0; kt <= qt; ++kt) {
      if (kt < qt) {
        stage(kt + 1, cur ^ 1);
        asm volatile("s_waitcnt vmcnt(8)" ::: "memory");   // retire stage(kt)
      } else {
        asm volatile("s_waitcnt vmcnt(0)" ::: "memory");
      }
      __builtin_amdgcn_s_barrier();
      __builtin_amdgcn_sched_barrier(0);

      float sv[4][4];
#pragma unroll
      for (int nt = 0; nt < 4; ++nt) {
        f32x4 sa = {};
#pragma unroll
        for (int kk = 0; kk < 4; ++kk) {
          int row = nt * 16 + lr;
          bf16x8 kf = *reinterpret_cast<const bf16x8*>(
              Ks[cur] + row * 128 + (((kk * 4 + lg) ^ (row & 7)) << 3));
          sa = __builtin_amdgcn_mfma_f32_16x16x32_bf16(qf[kk], kf, sa, 0, 0, 0);
        }
#pragma unroll
        for (int r = 0; r < 4; ++r) {
          float s = sa[r] * 0.088388347648318447f; // 1/sqrt(128)
          if (kt == qt && (nt * 16 + lr) > (wid * 16 + lg * 4 + r)) s -= 1e9f;
          sv[nt][r] = s;
        }
      }

      float tmax[4];
#pragma unroll
      for (int r = 0; r < 4; ++r)
        tmax[r] = fmaxf(fmaxf(sv[0][r], sv[1][r]), fmaxf(sv[2][r], sv[3][r]));
#pragma unroll
      for (int r = 0; r < 4; ++r) {
        tmax[r] = fmaxf(tmax[r], __shfl_xor(tmax[r], 1));
        tmax[r] = fmaxf(tmax[r], __shfl_xor(tmax[r], 2));
        tmax[r] = fmaxf(tmax[r], __shfl_xor(tmax[r], 4));
        tmax[r] = fmaxf(tmax[r], __shfl_xor(tmax[r], 8));
      }
      float fr[4], tsum[4];
#pragma unroll
      for (int r = 0; r < 4; ++r) {
        float mn = fmaxf(mrow[r], tmax[r]);
        fr[r] = __expf(mrow[r] - mn);
        mrow[r] = mn;
        tsum[r] = 0.f;
      }
#pragma unroll
      for (int nt = 0; nt < 4; ++nt) {
        int colc = nt * 2 + (lr >> 3);
#pragma unroll
        for (int r = 0; r < 4; ++r) {
          float p = __expf(sv[nt][r] - mrow[r]);
          tsum[r] += p;
          int row = wid * 16 + lg * 4 + r;
          Ps[row * 64 + ((colc ^ (row & 7)) << 3) + (lr & 7)] = f2bf(p);
        }
      }
#pragma unroll
      for (int r = 0; r < 4; ++r) {
        tsum[r] += __shfl_xor(tsum[r], 1);
        tsum[r] += __shfl_xor(tsum[r], 2);
        tsum[r] += __shfl_xor(tsum[r], 4);
        tsum[r] += __shfl_xor(tsum[r], 8);
        lsum[r] = lsum[r] * fr[r] + tsum[r];
      }
#pragma unroll
      for (int ct = 0; ct < 8; ++ct)
#pragma unroll
        for (int r = 0; r < 4; ++r)
          oacc[ct][r] *= fr[r];

      bf16x8 pf[2];
#pragma unroll
      for (int ks = 0; ks < 2; ++ks) {
        int row = wid * 16 + lr;
        pf[ks] = *reinterpret_cast<const bf16x8*>(
            Ps + row * 64 + (((ks * 4 + lg) ^ (row & 7)) << 3));
      }
#pragma unroll
      for (int ct = 0; ct < 8; ++ct) {
#pragma unroll
        for (int ks = 0; ks < 2; ++ks) {
          int row = ct * 16 + lr;
          bf16x8 vf = *reinterpret_cast<const bf16x8*>(
              Vs[cur] + row * 64 + (((ks * 4 + lg) ^ (row & 7)) << 3));
          oacc[ct] = __builtin_amdgcn_mfma_f32_16x16x32_bf16(pf[ks], vf, oacc[ct], 0, 0, 0);
        }
      }
      __builtin_amdgcn_s_barrier();           // readers of buf 'cur' done
      cur ^= 1;
    }

#pragma unroll
    for (int r = 0; r < 4; ++r) {
      float rl = 1.f / lsum[r];
      int qg = qt * 64 + wid * 16 + lg * 4 + r;
#pragma unroll
      for (int ct = 0; ct < 8; ++ct) {
        int d = ct * 16 + lr;
        attnb[((size_t)b * SS + qg) * HH + h * 128 + d] = f2bf(oacc[ct][r] * rl);
      }
    }
  }
}

// ---------------- launch ----------------

extern "C" void kernel_launch(void* const* d_in, const int* in_sizes, int n_in,
                              void* d_out, int out_size, void* d_ws, size_t ws_size,
                              hipStream_t stream) {
  const float* hs     = (const float*)d_in[0];
  const int*   pos    = (const int*)d_in[1];
  const float* qkv_w  = (const float*)d_in[3];
  const float* qkv_b  = (const float*)d_in[4];
  const float* o_w    = (const float*)d_in[5];
  float* out = (float*)d_out;
  char* ws = (char*)d_ws;

  unsigned short* hsb   = (unsigned short*)(ws);                  // 16 MB
  unsigned short* wqkvb = (unsigned short*)(ws + 16777216);       // 24 MB
  unsigned short* owb   = (unsigned short*)(ws + 41943040);       // 8 MB
  unsigned short* Qr    = (unsigned short*)(ws + 50331648);       // 16 MB
  unsigned short* Kr    = (unsigned short*)(ws + 67108864);       // 16 MB
  unsigned short* Vt    = (unsigned short*)(ws + 83886080);       // 16 MB
  unsigned short* attnb = (unsigned short*)(ws + 100663296);      // 16 MB
  float*          tab   = (float*)(ws + 117440512);               // 1 MB

  convert_bf16<<<2097152 / 256, 256, 0, stream>>>(hs, hsb, 2097152);
  convert_bf16<<<3145728 / 256, 256, 0, stream>>>(qkv_w, wqkvb, 3145728);
  convert_bf16<<<1048576 / 256, 256, 0, stream>>>(o_w, owb, 1048576);
  build_tab<<<512, 256, 0, stream>>>(tab);

  // QKV: BM=256, BN=192 -> grid 32x16 = 512 blocks = exactly 2 rounds.
  gemm_pipe<1, 8, 3><<<dim3(32, 16), 512, 0, stream>>>(hsb, wqkvb, qkv_b, nullptr, Qr, Kr, Vt, 2048);
  rope_inplace<<<4096, 256, 0, stream>>>(Qr, Kr, pos, tab);
  attn_fwd<<<dim3(16, 32), 256, 0, stream>>>(Qr, Kr, Vt, attnb);
  // O-proj: BM=128, BN=256 -> grid 8x32 = 256 blocks = exactly 1 round.
  gemm_pipe<0, 4, 4><<<dim3(8, 32), 512, 0, stream>>>(attnb, owb, nullptr, out, nullptr, nullptr, nullptr, 2048);
}